// Round 5
// baseline (567.075 us; speedup 1.0000x reference)
//
#include <hip/hip_runtime.h>
#include <hip/hip_bf16.h>

#define D_MODEL 1024
#define NHEADS 16
#define HDIM 64
#define BATCH 8
#define SEQ 512
#define NROWS 4096          // BATCH*SEQ
#define SCALE 0.125f
#define LN_EPS 1e-5f

typedef __attribute__((ext_vector_type(8))) short bf16x8;      // 8 bf16 (4 VGPRs)
typedef __attribute__((ext_vector_type(4))) float f32x4;
typedef __attribute__((ext_vector_type(8))) unsigned short u16x8;

static __device__ __forceinline__ float bf2f(unsigned short u) {
    return __uint_as_float(((unsigned int)u) << 16);
}
static __device__ __forceinline__ unsigned short f2bf(float f) {
    unsigned int x = __float_as_uint(f);
    unsigned int r = (x + 0x7fffu + ((x >> 16) & 1u)) >> 16;   // RNE
    return (unsigned short)r;
}

// ---------------------------------------------------------------------------
// fp32 -> bf16 bulk convert (weights)
// ---------------------------------------------------------------------------
__global__ void f32_to_bf16(const float* __restrict__ src, unsigned short* __restrict__ dst, int n4) {
    int idx = blockIdx.x * 256 + threadIdx.x;
    if (idx >= n4) return;
    float4 v = ((const float4*)src)[idx];
    ushort4 u;
    u.x = f2bf(v.x); u.y = f2bf(v.y); u.z = f2bf(v.z); u.w = f2bf(v.w);
    ((ushort4*)dst)[idx] = u;
}

// ---------------------------------------------------------------------------
// Bias: jax.image.resize(bias128, (512,512), 'bilinear')
// ---------------------------------------------------------------------------
static __device__ __forceinline__ float bias128(int a, int b) {
    float d = fabsf((float)(a - b));
    return expf(-d * 0.1f) - d * 0.05f;
}

__global__ void bias_kernel(float* __restrict__ bias) {
    int idx = blockIdx.x * 256 + threadIdx.x;
    if (idx >= 512 * 512) return;
    int qi = idx >> 9, kj = idx & 511;
    float fq = (qi + 0.5f) * 0.25f - 0.5f;
    float fk = (kj + 0.5f) * 0.25f - 0.5f;
    int iq = (int)floorf(fq); float tq = fq - (float)iq;
    int ik = (int)floorf(fk); float tk = fk - (float)ik;
    int iq0 = min(max(iq, 0), 127), iq1 = min(max(iq + 1, 0), 127);
    int ik0 = min(max(ik, 0), 127), ik1 = min(max(ik + 1, 0), 127);
    float v = (1.f - tq) * ((1.f - tk) * bias128(iq0, ik0) + tk * bias128(iq0, ik1))
            +        tq  * ((1.f - tk) * bias128(iq1, ik0) + tk * bias128(iq1, ik1));
    bias[idx] = v;
}

// ---------------------------------------------------------------------------
// LayerNorm of both streams -> bf16
// ---------------------------------------------------------------------------
__global__ void ln_kernel(const float* __restrict__ dec, const float* __restrict__ enc,
                          const float* __restrict__ gamma, const float* __restrict__ beta,
                          unsigned short* __restrict__ q_ln, unsigned short* __restrict__ kv_ln) {
    int row = blockIdx.x;                       // 0..8191
    const float* src = (row < NROWS) ? dec + (size_t)row * D_MODEL
                                     : enc + (size_t)(row - NROWS) * D_MODEL;
    unsigned short* dst = (row < NROWS) ? q_ln + (size_t)row * D_MODEL
                                        : kv_ln + (size_t)(row - NROWS) * D_MODEL;
    int t = threadIdx.x;
    float4 x = ((const float4*)src)[t];
    float s  = x.x + x.y + x.z + x.w;
    float ss = x.x * x.x + x.y * x.y + x.z * x.z + x.w * x.w;
    #pragma unroll
    for (int off = 32; off > 0; off >>= 1) {
        s  += __shfl_down(s, off);
        ss += __shfl_down(ss, off);
    }
    __shared__ float red_s[4], red_ss[4];
    int wid = t >> 6, lane = t & 63;
    if (lane == 0) { red_s[wid] = s; red_ss[wid] = ss; }
    __syncthreads();
    if (t == 0) {
        float S = red_s[0] + red_s[1] + red_s[2] + red_s[3];
        float SS = red_ss[0] + red_ss[1] + red_ss[2] + red_ss[3];
        red_s[0] = S; red_ss[0] = SS;
    }
    __syncthreads();
    float mu  = red_s[0] * (1.0f / 1024.0f);
    float var = red_ss[0] * (1.0f / 1024.0f) - mu * mu;
    float rstd = rsqrtf(var + LN_EPS);
    float4 g = ((const float4*)gamma)[t];
    float4 bb = ((const float4*)beta)[t];
    ushort4 u;
    u.x = f2bf((x.x - mu) * rstd * g.x + bb.x);
    u.y = f2bf((x.y - mu) * rstd * g.y + bb.y);
    u.z = f2bf((x.z - mu) * rstd * g.z + bb.z);
    u.w = f2bf((x.w - mu) * rstd * g.w + bb.w);
    ((ushort4*)dst)[t] = u;
}

// ===========================================================================
// Shared MFMA GEMM pattern: C(128x128) = A(128xK) @ W^T(128xK), bf16 in.
// 256 thr = 4 waves (2x2); wave does 64x64 as 4x4 MFMA 16x16 tiles.
// LDS union: staging (As,Bs stride 72) overlaid with C-bounce (stride 136).
// ===========================================================================
#define GSTR 72
#define CSTR 136   // multiple of 8 (16B-aligned rows for u16x8 epilogue reads)

union alignas(16) GemmSmem {
    struct { unsigned short A[128 * GSTR]; unsigned short B[128 * GSTR]; } ab;
    unsigned short C[128 * CSTR];   // 34816 shorts <= 36864
};

#define GEMM_MAIN_LOOP(Aptr, Bptr)                                             \
    __shared__ GemmSmem smem;                                                  \
    unsigned short* As = smem.ab.A;                                            \
    unsigned short* Bs = smem.ab.B;                                            \
    int tid = threadIdx.x;                                                     \
    int wave = tid >> 6, lane = tid & 63, quad = lane >> 4, c = lane & 15;     \
    int wr = wave >> 1, wc = wave & 1;                                         \
    int colg = tid & 7, r0 = tid >> 3;                                         \
    const unsigned short* Ab = (Aptr) + (size_t)(rt * 128 + r0) * 1024 + colg * 8; \
    const unsigned short* Bb = (Bptr) + (size_t)(ct * 128 + r0) * 1024 + colg * 8; \
    f32x4 acc[4][4];                                                           \
    _Pragma("unroll")                                                          \
    for (int i = 0; i < 4; ++i)                                                \
        _Pragma("unroll")                                                      \
        for (int j = 0; j < 4; ++j) acc[i][j] = (f32x4)0.f;                    \
    for (int kt = 0; kt < 16; ++kt) {                                          \
        int k0 = kt * 64;                                                      \
        __syncthreads();                                                       \
        _Pragma("unroll")                                                      \
        for (int j = 0; j < 4; ++j) {                                          \
            *(u16x8*)&As[(r0 + j * 32) * GSTR + colg * 8] =                    \
                *(const u16x8*)(Ab + (size_t)j * 32 * 1024 + k0);              \
            *(u16x8*)&Bs[(r0 + j * 32) * GSTR + colg * 8] =                    \
                *(const u16x8*)(Bb + (size_t)j * 32 * 1024 + k0);              \
        }                                                                      \
        __syncthreads();                                                       \
        _Pragma("unroll")                                                      \
        for (int kh = 0; kh < 2; ++kh) {                                       \
            bf16x8 af[4], bfr[4];                                              \
            _Pragma("unroll")                                                  \
            for (int i = 0; i < 4; ++i)                                        \
                af[i] = *(const bf16x8*)&As[(wr * 64 + i * 16 + c) * GSTR + kh * 32 + quad * 8]; \
            _Pragma("unroll")                                                  \
            for (int j = 0; j < 4; ++j)                                        \
                bfr[j] = *(const bf16x8*)&Bs[(wc * 64 + j * 16 + c) * GSTR + kh * 32 + quad * 8]; \
            _Pragma("unroll")                                                  \
            for (int i = 0; i < 4; ++i)                                        \
                _Pragma("unroll")                                              \
                for (int j = 0; j < 4; ++j)                                    \
                    acc[i][j] = __builtin_amdgcn_mfma_f32_16x16x32_bf16(af[i], bfr[j], acc[i][j], 0, 0, 0); \
        }                                                                      \
    }

// ---------------------------------------------------------------------------
// QKV GEMM (MFMA) + fused RoPE, LDS-bounce epilogue with wide stores.
// 1-D grid of 768, swizzled into 8(ct)x4(rt) super-tiles for L2 locality.
// ---------------------------------------------------------------------------
__global__ __launch_bounds__(256)
void qkv_gemm_mfma(const unsigned short* __restrict__ q_ln,
                   const unsigned short* __restrict__ kv_ln,
                   const unsigned short* __restrict__ Wb,
                   unsigned short* __restrict__ qo,
                   unsigned short* __restrict__ ko,
                   unsigned short* __restrict__ vo) {
    int bid = blockIdx.x;               // 0..767
    int st = bid >> 5, in = bid & 31;   // 24 super-tiles of 32 blocks
    int stc = st % 3, str = st / 3;
    int ct = stc * 8 + (in & 7);        // 0..23
    int rt = str * 4 + (in >> 3);       // 0..31
    int n0 = ct * 128;
    int section = n0 >> 10;             // 0=q 1=k 2=v (uniform per block)
    const unsigned short* A = (section == 0) ? q_ln : kv_ln;

    GEMM_MAIN_LOOP(A, Wb)

    // ---- epilogue: RoPE in-register, bounce through LDS, wide stores ----
    __syncthreads();                    // all waves done reading As/Bs
    if (section == 2) {
        #pragma unroll
        for (int i = 0; i < 4; ++i)
            #pragma unroll
            for (int reg = 0; reg < 4; ++reg) {
                int crow = (wr * 64 + i * 16 + quad * 4 + reg) * CSTR + wc * 64;
                #pragma unroll
                for (int j = 0; j < 4; ++j)
                    smem.C[crow + j * 16 + c] = f2bf(acc[i][j][reg]);
            }
    } else {
        float inv0 = expf(-0.2878231366f * (float)c);          // f = c
        float inv1 = expf(-0.2878231366f * (float)(16 + c));   // f = 16+c
        #pragma unroll
        for (int i = 0; i < 4; ++i)
            #pragma unroll
            for (int reg = 0; reg < 4; ++reg) {
                int mloc = wr * 64 + i * 16 + quad * 4 + reg;
                int crow = mloc * CSTR + wc * 64;
                float fl = (float)((rt * 128 + mloc) & 511);   // l
                float a0 = fl * inv0, a1 = fl * inv1;
                float c0 = cosf(a0), s0 = sinf(a0);
                float c1 = cosf(a1), s1 = sinf(a1);
                float e0 = acc[i][0][reg], o0 = acc[i][2][reg];
                float e1 = acc[i][1][reg], o1 = acc[i][3][reg];
                smem.C[crow + c]      = f2bf(e0 * c0 - o0 * s0);
                smem.C[crow + 32 + c] = f2bf(e0 * s0 + o0 * c0);
                smem.C[crow + 16 + c] = f2bf(e1 * c1 - o1 * s1);
                smem.C[crow + 48 + c] = f2bf(e1 * s1 + o1 * c1);
            }
    }
    __syncthreads();

    unsigned short* outp = (section == 0) ? qo : (section == 1) ? ko : vo;
    int rr = tid >> 1, ch = tid & 1;    // row 0..127, head-half 0/1
    int mm = rt * 128 + rr;
    int bb = mm >> 9, ll = mm & 511;
    int h = ((n0 & 1023) >> 6) + ch;
    unsigned short* orow = outp + (((size_t)bb * NHEADS + h) * SEQ + ll) * HDIM;
    const unsigned short* csrc = &smem.C[rr * CSTR + ch * 64];
    #pragma unroll
    for (int kc = 0; kc < 8; ++kc)
        *(u16x8*)(orow + kc * 8) = *(const u16x8*)(csrc + kc * 8);
}

// ---------------------------------------------------------------------------
// Projection 1 (MFMA): t = att @ Wout^T + b_out -> fp32 t_proj + bf16 t_bf
// grid (8, 32)
// ---------------------------------------------------------------------------
__global__ __launch_bounds__(256)
void out_gemm1_mfma(const unsigned short* __restrict__ att,
                    const unsigned short* __restrict__ Wob,
                    const float* __restrict__ b_out,
                    float* __restrict__ t_proj,
                    unsigned short* __restrict__ t_bf) {
    int ct = blockIdx.x, rt = blockIdx.y;

    GEMM_MAIN_LOOP(att, Wob)

    #pragma unroll
    for (int j = 0; j < 4; ++j) {
        int n = ct * 128 + wc * 64 + j * 16 + c;
        float bo = b_out[n];
        #pragma unroll
        for (int i = 0; i < 4; ++i)
            #pragma unroll
            for (int reg = 0; reg < 4; ++reg) {
                int mm = rt * 128 + wr * 64 + i * 16 + quad * 4 + reg;
                float v = acc[i][j][reg] + bo;
                t_proj[(size_t)mm * 1024 + n] = v;
                t_bf[(size_t)mm * 1024 + n] = f2bf(v);
            }
    }
}

// ---------------------------------------------------------------------------
// Projection 2 (MFMA): gz = t_bf @ Wgate^T + b_gate;
// out = sigmoid(gz)*t + (1-sigmoid)*residual
// grid (8, 32)
// ---------------------------------------------------------------------------
__global__ __launch_bounds__(256)
void out_gemm2_mfma(const unsigned short* __restrict__ t_bf,
                    const unsigned short* __restrict__ Wgb,
                    const float* __restrict__ b_gate,
                    const float* __restrict__ t_proj,
                    const float* __restrict__ residual,
                    float* __restrict__ out) {
    int ct = blockIdx.x, rt = blockIdx.y;

    GEMM_MAIN_LOOP(t_bf, Wgb)

    #pragma unroll
    for (int j = 0; j < 4; ++j) {
        int n = ct * 128 + wc * 64 + j * 16 + c;
        float bg = b_gate[n];
        #pragma unroll
        for (int i = 0; i < 4; ++i)
            #pragma unroll
            for (int reg = 0; reg < 4; ++reg) {
                int mm = rt * 128 + wr * 64 + i * 16 + quad * 4 + reg;
                float gz = acc[i][j][reg] + bg;
                float g = 1.0f / (1.0f + expf(-gz));
                float tv = t_proj[(size_t)mm * 1024 + n];
                float rv = residual[(size_t)mm * 1024 + n];
                out[(size_t)mm * 1024 + n] = g * tv + (1.0f - g) * rv;
            }
    }
}

// ---------------------------------------------------------------------------
// Flash attention, bf16 MFMA (16x16x32) — unchanged (verified)
// ---------------------------------------------------------------------------
#define KSTR 72

__global__ __launch_bounds__(256)
void attn_kernel(const unsigned short* __restrict__ q,
                 const unsigned short* __restrict__ k,
                 const unsigned short* __restrict__ v,
                 const float* __restrict__ bias,
                 unsigned short* __restrict__ attended) {
    int qt = blockIdx.x, h = blockIdx.y, b = blockIdx.z;
    __shared__ unsigned short Ks[64 * KSTR];
    __shared__ unsigned short Vt[64 * KSTR];
    __shared__ unsigned short Ps[64 * KSTR];
    __shared__ float af[64];
    __shared__ float lf[64];

    int tid = threadIdx.x;
    int wave = tid >> 6, lane = tid & 63;
    int quad = lane >> 4, c = lane & 15;
    int wb = wave * 16;
    size_t headbase = (((size_t)b * NHEADS + h) * SEQ) * HDIM;
    int q0 = qt * 64;

    const unsigned short* qrow = q + headbase + (size_t)(q0 + wb + c) * HDIM;
    bf16x8 aq0 = *(const bf16x8*)(qrow + quad * 8);
    bf16x8 aq1 = *(const bf16x8*)(qrow + 32 + quad * 8);

    int sr = tid >> 2, sc0 = (tid & 3) * 16;

    f32x4 oacc[4];
    #pragma unroll
    for (int t = 0; t < 4; ++t) oacc[t] = (f32x4)0.f;
    float mrow[4], lrow[4];
    #pragma unroll
    for (int r = 0; r < 4; ++r) { mrow[r] = -1e30f; lrow[r] = 0.f; }

    for (int kt = 0; kt < 8; ++kt) {
        int kv0 = kt * 64;
        __syncthreads();
        {
            const unsigned short* krow = k + headbase + (size_t)(kv0 + sr) * HDIM + sc0;
            const unsigned short* vrow = v + headbase + (size_t)(kv0 + sr) * HDIM + sc0;
            u16x8 ka = *(const u16x8*)(krow);
            u16x8 kb2 = *(const u16x8*)(krow + 8);
            u16x8 va = *(const u16x8*)(vrow);
            u16x8 vb2 = *(const u16x8*)(vrow + 8);
            *(u16x8*)&Ks[sr * KSTR + sc0] = ka;
            *(u16x8*)&Ks[sr * KSTR + sc0 + 8] = kb2;
            #pragma unroll
            for (int j = 0; j < 8; ++j) Vt[(sc0 + j) * KSTR + sr] = va[j];
            #pragma unroll
            for (int j = 0; j < 8; ++j) Vt[(sc0 + 8 + j) * KSTR + sr] = vb2[j];
        }
        __syncthreads();

        f32x4 sacc[4];
        #pragma unroll
        for (int nt = 0; nt < 4; ++nt) {
            const unsigned short* kbase = &Ks[(nt * 16 + c) * KSTR];
            bf16x8 b0 = *(const bf16x8*)(kbase + quad * 8);
            bf16x8 b1 = *(const bf16x8*)(kbase + 32 + quad * 8);
            f32x4 a = (f32x4)0.f;
            a = __builtin_amdgcn_mfma_f32_16x16x32_bf16(aq0, b0, a, 0, 0, 0);
            a = __builtin_amdgcn_mfma_f32_16x16x32_bf16(aq1, b1, a, 0, 0, 0);
            sacc[nt] = a;
        }

        const float* bbase = bias + (size_t)(q0 + wb + quad * 4) * 512 + kv0 + c;
        float tmax[4];
        #pragma unroll
        for (int r = 0; r < 4; ++r) tmax[r] = -1e30f;
        #pragma unroll
        for (int nt = 0; nt < 4; ++nt)
            #pragma unroll
            for (int r = 0; r < 4; ++r) {
                float s = sacc[nt][r] * SCALE + bbase[(size_t)r * 512 + nt * 16];
                sacc[nt][r] = s;
                tmax[r] = fmaxf(tmax[r], s);
            }
        #pragma unroll
        for (int r = 0; r < 4; ++r) {
            float t = tmax[r];
            t = fmaxf(t, __shfl_xor(t, 1));
            t = fmaxf(t, __shfl_xor(t, 2));
            t = fmaxf(t, __shfl_xor(t, 4));
            t = fmaxf(t, __shfl_xor(t, 8));
            tmax[r] = t;
        }
        float alpha[4];
        #pragma unroll
        for (int r = 0; r < 4; ++r) {
            float mnew = fmaxf(mrow[r], tmax[r]);
            alpha[r] = __expf(mrow[r] - mnew);
            mrow[r] = mnew;
        }
        float tsum[4];
        #pragma unroll
        for (int r = 0; r < 4; ++r) tsum[r] = 0.f;
        #pragma unroll
        for (int nt = 0; nt < 4; ++nt)
            #pragma unroll
            for (int r = 0; r < 4; ++r) {
                float p = __expf(sacc[nt][r] - mrow[r]);
                tsum[r] += p;
                Ps[(wb + quad * 4 + r) * KSTR + nt * 16 + c] = f2bf(p);
            }
        #pragma unroll
        for (int r = 0; r < 4; ++r) {
            float t = tsum[r];
            t += __shfl_xor(t, 1);
            t += __shfl_xor(t, 2);
            t += __shfl_xor(t, 4);
            t += __shfl_xor(t, 8);
            lrow[r] = lrow[r] * alpha[r] + t;
        }
        if (c == 0) {
            f32x4 av;
            av[0] = alpha[0]; av[1] = alpha[1]; av[2] = alpha[2]; av[3] = alpha[3];
            *(f32x4*)&af[wb + quad * 4] = av;
        }
        float myalpha = af[wb + c];
        #pragma unroll
        for (int t = 0; t < 4; ++t) oacc[t] *= myalpha;

        bf16x8 pb0 = *(const bf16x8*)&Ps[(wb + c) * KSTR + quad * 8];
        bf16x8 pb1 = *(const bf16x8*)&Ps[(wb + c) * KSTR + 32 + quad * 8];
        #pragma unroll
        for (int t = 0; t < 4; ++t) {
            const unsigned short* vbase = &Vt[(t * 16 + c) * KSTR];
            bf16x8 a0 = *(const bf16x8*)(vbase + quad * 8);
            bf16x8 a1 = *(const bf16x8*)(vbase + 32 + quad * 8);
            oacc[t] = __builtin_amdgcn_mfma_f32_16x16x32_bf16(a0, pb0, oacc[t], 0, 0, 0);
            oacc[t] = __builtin_amdgcn_mfma_f32_16x16x32_bf16(a1, pb1, oacc[t], 0, 0, 0);
        }
    }

    if (c == 0) {
        f32x4 lv;
        lv[0] = lrow[0]; lv[1] = lrow[1]; lv[2] = lrow[2]; lv[3] = lrow[3];
        *(f32x4*)&lf[wb + quad * 4] = lv;
    }
    float invl = 1.0f / lf[wb + c];
    unsigned short* drow = attended + ((size_t)b * SEQ + (q0 + wb + c)) * D_MODEL + h * HDIM;
    #pragma unroll
    for (int t = 0; t < 4; ++t) {
        ushort4 o;
        o.x = f2bf(oacc[t][0] * invl);
        o.y = f2bf(oacc[t][1] * invl);
        o.z = f2bf(oacc[t][2] * invl);
        o.w = f2bf(oacc[t][3] * invl);
        *(ushort4*)(drow + t * 16 + quad * 4) = o;
    }
}

extern "C" void kernel_launch(void* const* d_in, const int* in_sizes, int n_in,
                              void* d_out, int out_size, void* d_ws, size_t ws_size,
                              hipStream_t stream) {
    const float* dec    = (const float*)d_in[0];
    const float* enc    = (const float*)d_in[1];
    const float* Wqkv   = (const float*)d_in[2];
    const float* Wout   = (const float*)d_in[3];
    const float* b_out  = (const float*)d_in[4];
    const float* Wgate  = (const float*)d_in[5];
    const float* b_gate = (const float*)d_in[6];
    const float* gamma  = (const float*)d_in[7];
    const float* beta   = (const float*)d_in[8];
    float* out = (float*)d_out;

    char* ws = (char*)d_ws;
    const size_t MB = 1024 * 1024;
    unsigned short* q_ln    = (unsigned short*)(ws + 0 * MB);
    unsigned short* kv_ln   = (unsigned short*)(ws + 8 * MB);
    unsigned short* qb      = (unsigned short*)(ws + 16 * MB);
    unsigned short* kb      = (unsigned short*)(ws + 24 * MB);
    unsigned short* vb      = (unsigned short*)(ws + 32 * MB);
    unsigned short* Wqkv_bf = (unsigned short*)(ws + 40 * MB);
    float*          bias    = (float*)(ws + 46 * MB);
    unsigned short* att     = (unsigned short*)(ws + 0 * MB);
    float*          t_proj  = (float*)(ws + 8 * MB);
    unsigned short* t_bf    = (unsigned short*)(ws + 24 * MB);
    unsigned short* Wout_bf = (unsigned short*)(ws + 32 * MB);
    unsigned short* Wgate_bf= (unsigned short*)(ws + 34 * MB);

    bias_kernel<<<1024, 256, 0, stream>>>(bias);
    ln_kernel<<<8192, 256, 0, stream>>>(dec, enc, gamma, beta, q_ln, kv_ln);
    f32_to_bf16<<<3072, 256, 0, stream>>>(Wqkv, Wqkv_bf, 3072 * 1024 / 4);
    qkv_gemm_mfma<<<768, 256, 0, stream>>>(q_ln, kv_ln, Wqkv_bf, qb, kb, vb);
    attn_kernel<<<dim3(8, 16, 8), 256, 0, stream>>>(qb, kb, vb, bias, att);
    f32_to_bf16<<<1024, 256, 0, stream>>>(Wout, Wout_bf, 1024 * 1024 / 4);
    f32_to_bf16<<<1024, 256, 0, stream>>>(Wgate, Wgate_bf, 1024 * 1024 / 4);
    out_gemm1_mfma<<<dim3(8, 32), 256, 0, stream>>>(att, Wout_bf, b_out, t_proj, t_bf);
    out_gemm2_mfma<<<dim3(8, 32), 256, 0, stream>>>(t_bf, Wgate_bf, b_gate, t_proj, dec, out);
}

// Round 6
// 562.465 us; speedup vs baseline: 1.0082x; 1.0082x over previous
//
#include <hip/hip_runtime.h>
#include <hip/hip_bf16.h>

#define D_MODEL 1024
#define NHEADS 16
#define HDIM 64
#define BATCH 8
#define SEQ 512
#define NROWS 4096          // BATCH*SEQ
#define SCALE 0.125f
#define LN_EPS 1e-5f

typedef __attribute__((ext_vector_type(8))) short bf16x8;      // 8 bf16 (4 VGPRs)
typedef __attribute__((ext_vector_type(4))) float f32x4;
typedef __attribute__((ext_vector_type(8))) unsigned short u16x8;

static __device__ __forceinline__ float bf2f(unsigned short u) {
    return __uint_as_float(((unsigned int)u) << 16);
}
static __device__ __forceinline__ unsigned short f2bf(float f) {
    unsigned int x = __float_as_uint(f);
    unsigned int r = (x + 0x7fffu + ((x >> 16) & 1u)) >> 16;   // RNE
    return (unsigned short)r;
}

// ---------------------------------------------------------------------------
// fp32 -> bf16 bulk convert (weights)
// ---------------------------------------------------------------------------
__global__ void f32_to_bf16(const float* __restrict__ src, unsigned short* __restrict__ dst, int n4) {
    int idx = blockIdx.x * 256 + threadIdx.x;
    if (idx >= n4) return;
    float4 v = ((const float4*)src)[idx];
    ushort4 u;
    u.x = f2bf(v.x); u.y = f2bf(v.y); u.z = f2bf(v.z); u.w = f2bf(v.w);
    ((ushort4*)dst)[idx] = u;
}

// ---------------------------------------------------------------------------
// Bias: jax.image.resize(bias128, (512,512), 'bilinear')
// ---------------------------------------------------------------------------
static __device__ __forceinline__ float bias128(int a, int b) {
    float d = fabsf((float)(a - b));
    return expf(-d * 0.1f) - d * 0.05f;
}

__global__ void bias_kernel(float* __restrict__ bias) {
    int idx = blockIdx.x * 256 + threadIdx.x;
    if (idx >= 512 * 512) return;
    int qi = idx >> 9, kj = idx & 511;
    float fq = (qi + 0.5f) * 0.25f - 0.5f;
    float fk = (kj + 0.5f) * 0.25f - 0.5f;
    int iq = (int)floorf(fq); float tq = fq - (float)iq;
    int ik = (int)floorf(fk); float tk = fk - (float)ik;
    int iq0 = min(max(iq, 0), 127), iq1 = min(max(iq + 1, 0), 127);
    int ik0 = min(max(ik, 0), 127), ik1 = min(max(ik + 1, 0), 127);
    float v = (1.f - tq) * ((1.f - tk) * bias128(iq0, ik0) + tk * bias128(iq0, ik1))
            +        tq  * ((1.f - tk) * bias128(iq1, ik0) + tk * bias128(iq1, ik1));
    bias[idx] = v;
}

// ---------------------------------------------------------------------------
// LayerNorm of both streams -> bf16
// ---------------------------------------------------------------------------
__global__ void ln_kernel(const float* __restrict__ dec, const float* __restrict__ enc,
                          const float* __restrict__ gamma, const float* __restrict__ beta,
                          unsigned short* __restrict__ q_ln, unsigned short* __restrict__ kv_ln) {
    int row = blockIdx.x;                       // 0..8191
    const float* src = (row < NROWS) ? dec + (size_t)row * D_MODEL
                                     : enc + (size_t)(row - NROWS) * D_MODEL;
    unsigned short* dst = (row < NROWS) ? q_ln + (size_t)row * D_MODEL
                                        : kv_ln + (size_t)(row - NROWS) * D_MODEL;
    int t = threadIdx.x;
    float4 x = ((const float4*)src)[t];
    float s  = x.x + x.y + x.z + x.w;
    float ss = x.x * x.x + x.y * x.y + x.z * x.z + x.w * x.w;
    #pragma unroll
    for (int off = 32; off > 0; off >>= 1) {
        s  += __shfl_down(s, off);
        ss += __shfl_down(ss, off);
    }
    __shared__ float red_s[4], red_ss[4];
    int wid = t >> 6, lane = t & 63;
    if (lane == 0) { red_s[wid] = s; red_ss[wid] = ss; }
    __syncthreads();
    if (t == 0) {
        float S = red_s[0] + red_s[1] + red_s[2] + red_s[3];
        float SS = red_ss[0] + red_ss[1] + red_ss[2] + red_ss[3];
        red_s[0] = S; red_ss[0] = SS;
    }
    __syncthreads();
    float mu  = red_s[0] * (1.0f / 1024.0f);
    float var = red_ss[0] * (1.0f / 1024.0f) - mu * mu;
    float rstd = rsqrtf(var + LN_EPS);
    float4 g = ((const float4*)gamma)[t];
    float4 bb = ((const float4*)beta)[t];
    ushort4 u;
    u.x = f2bf((x.x - mu) * rstd * g.x + bb.x);
    u.y = f2bf((x.y - mu) * rstd * g.y + bb.y);
    u.z = f2bf((x.z - mu) * rstd * g.z + bb.z);
    u.w = f2bf((x.w - mu) * rstd * g.w + bb.w);
    ((ushort4*)dst)[t] = u;
}

// ===========================================================================
// Shared MFMA GEMM pattern: C(128x128) = A(128xK) @ W^T(128xK), bf16 in.
// 256 thr = 4 waves (2x2); wave does 64x64 as 4x4 MFMA 16x16 tiles.
// LDS union: staging (As,Bs stride 72) overlaid with C-bounce (stride 136).
// Register budget: acc 64 + af 16 + bfr 4 + staging/addr -> needs
// __launch_bounds__(256,1) so the allocator is NOT capped by the LDS-implied
// 4-blocks/CU occupancy target (R5: cap at 68 VGPR spilled acc to scratch ->
// 1.25 GB HBM writes, kernel HBM-bound at 4.5 TB/s).
// ===========================================================================
#define GSTR 72
#define CSTR 136   // multiple of 8 (16B-aligned rows for u16x8 epilogue reads)

union alignas(16) GemmSmem {
    struct { unsigned short A[128 * GSTR]; unsigned short B[128 * GSTR]; } ab;
    unsigned short C[128 * CSTR];   // 34816 shorts <= 36864
};

#define GEMM_MAIN_LOOP(Aptr, Bptr)                                             \
    __shared__ GemmSmem smem;                                                  \
    unsigned short* As = smem.ab.A;                                            \
    unsigned short* Bs = smem.ab.B;                                            \
    int tid = threadIdx.x;                                                     \
    int wave = tid >> 6, lane = tid & 63, quad = lane >> 4, c = lane & 15;     \
    int wr = wave >> 1, wc = wave & 1;                                         \
    int colg = tid & 7, r0 = tid >> 3;                                         \
    const unsigned short* Ab = (Aptr) + (size_t)(rt * 128 + r0) * 1024 + colg * 8; \
    const unsigned short* Bb = (Bptr) + (size_t)(ct * 128 + r0) * 1024 + colg * 8; \
    f32x4 acc[4][4];                                                           \
    _Pragma("unroll")                                                          \
    for (int i = 0; i < 4; ++i)                                                \
        _Pragma("unroll")                                                      \
        for (int j = 0; j < 4; ++j) acc[i][j] = (f32x4)0.f;                    \
    for (int kt = 0; kt < 16; ++kt) {                                          \
        int k0 = kt * 64;                                                      \
        __syncthreads();                                                       \
        _Pragma("unroll")                                                      \
        for (int j = 0; j < 4; ++j) {                                          \
            *(u16x8*)&As[(r0 + j * 32) * GSTR + colg * 8] =                    \
                *(const u16x8*)(Ab + (size_t)j * 32 * 1024 + k0);              \
            *(u16x8*)&Bs[(r0 + j * 32) * GSTR + colg * 8] =                    \
                *(const u16x8*)(Bb + (size_t)j * 32 * 1024 + k0);              \
        }                                                                      \
        __syncthreads();                                                       \
        _Pragma("unroll")                                                      \
        for (int kh = 0; kh < 2; ++kh) {                                       \
            bf16x8 af[4];                                                      \
            _Pragma("unroll")                                                  \
            for (int i = 0; i < 4; ++i)                                        \
                af[i] = *(const bf16x8*)&As[(wr * 64 + i * 16 + c) * GSTR + kh * 32 + quad * 8]; \
            _Pragma("unroll")                                                  \
            for (int j = 0; j < 4; ++j) {                                      \
                bf16x8 bfr = *(const bf16x8*)&Bs[(wc * 64 + j * 16 + c) * GSTR + kh * 32 + quad * 8]; \
                _Pragma("unroll")                                              \
                for (int i = 0; i < 4; ++i)                                    \
                    acc[i][j] = __builtin_amdgcn_mfma_f32_16x16x32_bf16(af[i], bfr, acc[i][j], 0, 0, 0); \
            }                                                                  \
        }                                                                      \
    }

// ---------------------------------------------------------------------------
// QKV GEMM (MFMA) + fused RoPE, LDS-bounce epilogue with wide stores.
// 1-D grid of 768, swizzled into 8(ct)x4(rt) super-tiles for L2 locality.
// ---------------------------------------------------------------------------
__global__ __launch_bounds__(256, 1)
void qkv_gemm_mfma(const unsigned short* __restrict__ q_ln,
                   const unsigned short* __restrict__ kv_ln,
                   const unsigned short* __restrict__ Wb,
                   unsigned short* __restrict__ qo,
                   unsigned short* __restrict__ ko,
                   unsigned short* __restrict__ vo) {
    int bid = blockIdx.x;               // 0..767
    int st = bid >> 5, in = bid & 31;   // 24 super-tiles of 32 blocks
    int stc = st % 3, str = st / 3;
    int ct = stc * 8 + (in & 7);        // 0..23
    int rt = str * 4 + (in >> 3);       // 0..31
    int n0 = ct * 128;
    int section = n0 >> 10;             // 0=q 1=k 2=v (uniform per block)
    const unsigned short* A = (section == 0) ? q_ln : kv_ln;

    GEMM_MAIN_LOOP(A, Wb)

    // ---- epilogue: RoPE in-register, bounce through LDS, wide stores ----
    __syncthreads();                    // all waves done reading As/Bs
    if (section == 2) {
        #pragma unroll
        for (int i = 0; i < 4; ++i)
            #pragma unroll
            for (int reg = 0; reg < 4; ++reg) {
                int crow = (wr * 64 + i * 16 + quad * 4 + reg) * CSTR + wc * 64;
                #pragma unroll
                for (int j = 0; j < 4; ++j)
                    smem.C[crow + j * 16 + c] = f2bf(acc[i][j][reg]);
            }
    } else {
        float inv0 = expf(-0.2878231366f * (float)c);          // f = c
        float inv1 = expf(-0.2878231366f * (float)(16 + c));   // f = 16+c
        #pragma unroll
        for (int i = 0; i < 4; ++i)
            #pragma unroll
            for (int reg = 0; reg < 4; ++reg) {
                int mloc = wr * 64 + i * 16 + quad * 4 + reg;
                int crow = mloc * CSTR + wc * 64;
                float fl = (float)((rt * 128 + mloc) & 511);   // l
                float a0 = fl * inv0, a1 = fl * inv1;
                float c0 = cosf(a0), s0 = sinf(a0);
                float c1 = cosf(a1), s1 = sinf(a1);
                float e0 = acc[i][0][reg], o0 = acc[i][2][reg];
                float e1 = acc[i][1][reg], o1 = acc[i][3][reg];
                smem.C[crow + c]      = f2bf(e0 * c0 - o0 * s0);
                smem.C[crow + 32 + c] = f2bf(e0 * s0 + o0 * c0);
                smem.C[crow + 16 + c] = f2bf(e1 * c1 - o1 * s1);
                smem.C[crow + 48 + c] = f2bf(e1 * s1 + o1 * c1);
            }
    }
    __syncthreads();

    unsigned short* outp = (section == 0) ? qo : (section == 1) ? ko : vo;
    int rr = tid >> 1, ch = tid & 1;    // row 0..127, head-half 0/1
    int mm = rt * 128 + rr;
    int bb = mm >> 9, ll = mm & 511;
    int h = ((n0 & 1023) >> 6) + ch;
    unsigned short* orow = outp + (((size_t)bb * NHEADS + h) * SEQ + ll) * HDIM;
    const unsigned short* csrc = &smem.C[rr * CSTR + ch * 64];
    #pragma unroll
    for (int kc = 0; kc < 8; ++kc)
        *(u16x8*)(orow + kc * 8) = *(const u16x8*)(csrc + kc * 8);
}

// ---------------------------------------------------------------------------
// Projection 1 (MFMA): t = att @ Wout^T + b_out -> fp32 t_proj + bf16 t_bf
// grid (8, 32)
// ---------------------------------------------------------------------------
__global__ __launch_bounds__(256, 1)
void out_gemm1_mfma(const unsigned short* __restrict__ att,
                    const unsigned short* __restrict__ Wob,
                    const float* __restrict__ b_out,
                    float* __restrict__ t_proj,
                    unsigned short* __restrict__ t_bf) {
    int ct = blockIdx.x, rt = blockIdx.y;

    GEMM_MAIN_LOOP(att, Wob)

    #pragma unroll
    for (int j = 0; j < 4; ++j) {
        int n = ct * 128 + wc * 64 + j * 16 + c;
        float bo = b_out[n];
        #pragma unroll
        for (int i = 0; i < 4; ++i)
            #pragma unroll
            for (int reg = 0; reg < 4; ++reg) {
                int mm = rt * 128 + wr * 64 + i * 16 + quad * 4 + reg;
                float v = acc[i][j][reg] + bo;
                t_proj[(size_t)mm * 1024 + n] = v;
                t_bf[(size_t)mm * 1024 + n] = f2bf(v);
            }
    }
}

// ---------------------------------------------------------------------------
// Projection 2 (MFMA): gz = t_bf @ Wgate^T + b_gate;
// out = sigmoid(gz)*t + (1-sigmoid)*residual
// grid (8, 32)
// ---------------------------------------------------------------------------
__global__ __launch_bounds__(256, 1)
void out_gemm2_mfma(const unsigned short* __restrict__ t_bf,
                    const unsigned short* __restrict__ Wgb,
                    const float* __restrict__ b_gate,
                    const float* __restrict__ t_proj,
                    const float* __restrict__ residual,
                    float* __restrict__ out) {
    int ct = blockIdx.x, rt = blockIdx.y;

    GEMM_MAIN_LOOP(t_bf, Wgb)

    #pragma unroll
    for (int j = 0; j < 4; ++j) {
        int n = ct * 128 + wc * 64 + j * 16 + c;
        float bg = b_gate[n];
        #pragma unroll
        for (int i = 0; i < 4; ++i)
            #pragma unroll
            for (int reg = 0; reg < 4; ++reg) {
                int mm = rt * 128 + wr * 64 + i * 16 + quad * 4 + reg;
                float gz = acc[i][j][reg] + bg;
                float g = 1.0f / (1.0f + expf(-gz));
                float tv = t_proj[(size_t)mm * 1024 + n];
                float rv = residual[(size_t)mm * 1024 + n];
                out[(size_t)mm * 1024 + n] = g * tv + (1.0f - g) * rv;
            }
    }
}

// ---------------------------------------------------------------------------
// Flash attention, bf16 MFMA (16x16x32) — unchanged (verified)
// ---------------------------------------------------------------------------
#define KSTR 72

__global__ __launch_bounds__(256)
void attn_kernel(const unsigned short* __restrict__ q,
                 const unsigned short* __restrict__ k,
                 const unsigned short* __restrict__ v,
                 const float* __restrict__ bias,
                 unsigned short* __restrict__ attended) {
    int qt = blockIdx.x, h = blockIdx.y, b = blockIdx.z;
    __shared__ unsigned short Ks[64 * KSTR];
    __shared__ unsigned short Vt[64 * KSTR];
    __shared__ unsigned short Ps[64 * KSTR];
    __shared__ float af[64];
    __shared__ float lf[64];

    int tid = threadIdx.x;
    int wave = tid >> 6, lane = tid & 63;
    int quad = lane >> 4, c = lane & 15;
    int wb = wave * 16;
    size_t headbase = (((size_t)b * NHEADS + h) * SEQ) * HDIM;
    int q0 = qt * 64;

    const unsigned short* qrow = q + headbase + (size_t)(q0 + wb + c) * HDIM;
    bf16x8 aq0 = *(const bf16x8*)(qrow + quad * 8);
    bf16x8 aq1 = *(const bf16x8*)(qrow + 32 + quad * 8);

    int sr = tid >> 2, sc0 = (tid & 3) * 16;

    f32x4 oacc[4];
    #pragma unroll
    for (int t = 0; t < 4; ++t) oacc[t] = (f32x4)0.f;
    float mrow[4], lrow[4];
    #pragma unroll
    for (int r = 0; r < 4; ++r) { mrow[r] = -1e30f; lrow[r] = 0.f; }

    for (int kt = 0; kt < 8; ++kt) {
        int kv0 = kt * 64;
        __syncthreads();
        {
            const unsigned short* krow = k + headbase + (size_t)(kv0 + sr) * HDIM + sc0;
            const unsigned short* vrow = v + headbase + (size_t)(kv0 + sr) * HDIM + sc0;
            u16x8 ka = *(const u16x8*)(krow);
            u16x8 kb2 = *(const u16x8*)(krow + 8);
            u16x8 va = *(const u16x8*)(vrow);
            u16x8 vb2 = *(const u16x8*)(vrow + 8);
            *(u16x8*)&Ks[sr * KSTR + sc0] = ka;
            *(u16x8*)&Ks[sr * KSTR + sc0 + 8] = kb2;
            #pragma unroll
            for (int j = 0; j < 8; ++j) Vt[(sc0 + j) * KSTR + sr] = va[j];
            #pragma unroll
            for (int j = 0; j < 8; ++j) Vt[(sc0 + 8 + j) * KSTR + sr] = vb2[j];
        }
        __syncthreads();

        f32x4 sacc[4];
        #pragma unroll
        for (int nt = 0; nt < 4; ++nt) {
            const unsigned short* kbase = &Ks[(nt * 16 + c) * KSTR];
            bf16x8 b0 = *(const bf16x8*)(kbase + quad * 8);
            bf16x8 b1 = *(const bf16x8*)(kbase + 32 + quad * 8);
            f32x4 a = (f32x4)0.f;
            a = __builtin_amdgcn_mfma_f32_16x16x32_bf16(aq0, b0, a, 0, 0, 0);
            a = __builtin_amdgcn_mfma_f32_16x16x32_bf16(aq1, b1, a, 0, 0, 0);
            sacc[nt] = a;
        }

        const float* bbase = bias + (size_t)(q0 + wb + quad * 4) * 512 + kv0 + c;
        float tmax[4];
        #pragma unroll
        for (int r = 0; r < 4; ++r) tmax[r] = -1e30f;
        #pragma unroll
        for (int nt = 0; nt < 4; ++nt)
            #pragma unroll
            for (int r = 0; r < 4; ++r) {
                float s = sacc[nt][r] * SCALE + bbase[(size_t)r * 512 + nt * 16];
                sacc[nt][r] = s;
                tmax[r] = fmaxf(tmax[r], s);
            }
        #pragma unroll
        for (int r = 0; r < 4; ++r) {
            float t = tmax[r];
            t = fmaxf(t, __shfl_xor(t, 1));
            t = fmaxf(t, __shfl_xor(t, 2));
            t = fmaxf(t, __shfl_xor(t, 4));
            t = fmaxf(t, __shfl_xor(t, 8));
            tmax[r] = t;
        }
        float alpha[4];
        #pragma unroll
        for (int r = 0; r < 4; ++r) {
            float mnew = fmaxf(mrow[r], tmax[r]);
            alpha[r] = __expf(mrow[r] - mnew);
            mrow[r] = mnew;
        }
        float tsum[4];
        #pragma unroll
        for (int r = 0; r < 4; ++r) tsum[r] = 0.f;
        #pragma unroll
        for (int nt = 0; nt < 4; ++nt)
            #pragma unroll
            for (int r = 0; r < 4; ++r) {
                float p = __expf(sacc[nt][r] - mrow[r]);
                tsum[r] += p;
                Ps[(wb + quad * 4 + r) * KSTR + nt * 16 + c] = f2bf(p);
            }
        #pragma unroll
        for (int r = 0; r < 4; ++r) {
            float t = tsum[r];
            t += __shfl_xor(t, 1);
            t += __shfl_xor(t, 2);
            t += __shfl_xor(t, 4);
            t += __shfl_xor(t, 8);
            lrow[r] = lrow[r] * alpha[r] + t;
        }
        if (c == 0) {
            f32x4 av;
            av[0] = alpha[0]; av[1] = alpha[1]; av[2] = alpha[2]; av[3] = alpha[3];
            *(f32x4*)&af[wb + quad * 4] = av;
        }
        float myalpha = af[wb + c];
        #pragma unroll
        for (int t = 0; t < 4; ++t) oacc[t] *= myalpha;

        bf16x8 pb0 = *(const bf16x8*)&Ps[(wb + c) * KSTR + quad * 8];
        bf16x8 pb1 = *(const bf16x8*)&Ps[(wb + c) * KSTR + 32 + quad * 8];
        #pragma unroll
        for (int t = 0; t < 4; ++t) {
            const unsigned short* vbase = &Vt[(t * 16 + c) * KSTR];
            bf16x8 a0 = *(const bf16x8*)(vbase + quad * 8);
            bf16x8 a1 = *(const bf16x8*)(vbase + 32 + quad * 8);
            oacc[t] = __builtin_amdgcn_mfma_f32_16x16x32_bf16(a0, pb0, oacc[t], 0, 0, 0);
            oacc[t] = __builtin_amdgcn_mfma_f32_16x16x32_bf16(a1, pb1, oacc[t], 0, 0, 0);
        }
    }

    if (c == 0) {
        f32x4 lv;
        lv[0] = lrow[0]; lv[1] = lrow[1]; lv[2] = lrow[2]; lv[3] = lrow[3];
        *(f32x4*)&lf[wb + quad * 4] = lv;
    }
    float invl = 1.0f / lf[wb + c];
    unsigned short* drow = attended + ((size_t)b * SEQ + (q0 + wb + c)) * D_MODEL + h * HDIM;
    #pragma unroll
    for (int t = 0; t < 4; ++t) {
        ushort4 o;
        o.x = f2bf(oacc[t][0] * invl);
        o.y = f2bf(oacc[t][1] * invl);
        o.z = f2bf(oacc[t][2] * invl);
        o.w = f2bf(oacc[t][3] * invl);
        *(ushort4*)(drow + t * 16 + quad * 4) = o;
    }
}

extern "C" void kernel_launch(void* const* d_in, const int* in_sizes, int n_in,
                              void* d_out, int out_size, void* d_ws, size_t ws_size,
                              hipStream_t stream) {
    const float* dec    = (const float*)d_in[0];
    const float* enc    = (const float*)d_in[1];
    const float* Wqkv   = (const float*)d_in[2];
    const float* Wout   = (const float*)d_in[3];
    const float* b_out  = (const float*)d_in[4];
    const float* Wgate  = (const float*)d_in[5];
    const float* b_gate = (const float*)d_in[6];
    const float* gamma  = (const float*)d_in[7];
    const float* beta   = (const float*)d_in[8];
    float* out = (float*)d_out;

    char* ws = (char*)d_ws;
    const size_t MB = 1024 * 1024;
    unsigned short* q_ln    = (unsigned short*)(ws + 0 * MB);
    unsigned short* kv_ln   = (unsigned short*)(ws + 8 * MB);
    unsigned short* qb      = (unsigned short*)(ws + 16 * MB);
    unsigned short* kb      = (unsigned short*)(ws + 24 * MB);
    unsigned short* vb      = (unsigned short*)(ws + 32 * MB);
    unsigned short* Wqkv_bf = (unsigned short*)(ws + 40 * MB);
    float*          bias    = (float*)(ws + 46 * MB);
    unsigned short* att     = (unsigned short*)(ws + 0 * MB);
    float*          t_proj  = (float*)(ws + 8 * MB);
    unsigned short* t_bf    = (unsigned short*)(ws + 24 * MB);
    unsigned short* Wout_bf = (unsigned short*)(ws + 32 * MB);
    unsigned short* Wgate_bf= (unsigned short*)(ws + 34 * MB);

    bias_kernel<<<1024, 256, 0, stream>>>(bias);
    ln_kernel<<<8192, 256, 0, stream>>>(dec, enc, gamma, beta, q_ln, kv_ln);
    f32_to_bf16<<<3072, 256, 0, stream>>>(Wqkv, Wqkv_bf, 3072 * 1024 / 4);
    qkv_gemm_mfma<<<768, 256, 0, stream>>>(q_ln, kv_ln, Wqkv_bf, qb, kb, vb);
    attn_kernel<<<dim3(8, 16, 8), 256, 0, stream>>>(qb, kb, vb, bias, att);
    f32_to_bf16<<<1024, 256, 0, stream>>>(Wout, Wout_bf, 1024 * 1024 / 4);
    f32_to_bf16<<<1024, 256, 0, stream>>>(Wgate, Wgate_bf, 1024 * 1024 / 4);
    out_gemm1_mfma<<<dim3(8, 32), 256, 0, stream>>>(att, Wout_bf, b_out, t_proj, t_bf);
    out_gemm2_mfma<<<dim3(8, 32), 256, 0, stream>>>(t_bf, Wgate_bf, b_gate, t_proj, dec, out);
}

// Round 7
// 280.419 us; speedup vs baseline: 2.0222x; 2.0058x over previous
//
#include <hip/hip_runtime.h>
#include <hip/hip_bf16.h>

#define D_MODEL 1024
#define NHEADS 16
#define HDIM 64
#define BATCH 8
#define SEQ 512
#define NROWS 4096          // BATCH*SEQ
#define SCALE 0.125f
#define LN_EPS 1e-5f

typedef __attribute__((ext_vector_type(8))) short bf16x8;      // 8 bf16 (4 VGPRs)
typedef __attribute__((ext_vector_type(4))) float f32x4;
typedef __attribute__((ext_vector_type(8))) unsigned short u16x8;

static __device__ __forceinline__ float bf2f(unsigned short u) {
    return __uint_as_float(((unsigned int)u) << 16);
}
static __device__ __forceinline__ unsigned short f2bf(float f) {
    unsigned int x = __float_as_uint(f);
    unsigned int r = (x + 0x7fffu + ((x >> 16) & 1u)) >> 16;   // RNE
    return (unsigned short)r;
}

// ---------------------------------------------------------------------------
// fp32 -> bf16 bulk convert (weights)
// ---------------------------------------------------------------------------
__global__ void f32_to_bf16(const float* __restrict__ src, unsigned short* __restrict__ dst, int n4) {
    int idx = blockIdx.x * 256 + threadIdx.x;
    if (idx >= n4) return;
    float4 v = ((const float4*)src)[idx];
    ushort4 u;
    u.x = f2bf(v.x); u.y = f2bf(v.y); u.z = f2bf(v.z); u.w = f2bf(v.w);
    ((ushort4*)dst)[idx] = u;
}

// ---------------------------------------------------------------------------
// Bias: jax.image.resize(bias128, (512,512), 'bilinear')
// ---------------------------------------------------------------------------
static __device__ __forceinline__ float bias128(int a, int b) {
    float d = fabsf((float)(a - b));
    return expf(-d * 0.1f) - d * 0.05f;
}

__global__ void bias_kernel(float* __restrict__ bias) {
    int idx = blockIdx.x * 256 + threadIdx.x;
    if (idx >= 512 * 512) return;
    int qi = idx >> 9, kj = idx & 511;
    float fq = (qi + 0.5f) * 0.25f - 0.5f;
    float fk = (kj + 0.5f) * 0.25f - 0.5f;
    int iq = (int)floorf(fq); float tq = fq - (float)iq;
    int ik = (int)floorf(fk); float tk = fk - (float)ik;
    int iq0 = min(max(iq, 0), 127), iq1 = min(max(iq + 1, 0), 127);
    int ik0 = min(max(ik, 0), 127), ik1 = min(max(ik + 1, 0), 127);
    float v = (1.f - tq) * ((1.f - tk) * bias128(iq0, ik0) + tk * bias128(iq0, ik1))
            +        tq  * ((1.f - tk) * bias128(iq1, ik0) + tk * bias128(iq1, ik1));
    bias[idx] = v;
}

// ---------------------------------------------------------------------------
// LayerNorm of both streams -> bf16
// ---------------------------------------------------------------------------
__global__ void ln_kernel(const float* __restrict__ dec, const float* __restrict__ enc,
                          const float* __restrict__ gamma, const float* __restrict__ beta,
                          unsigned short* __restrict__ q_ln, unsigned short* __restrict__ kv_ln) {
    int row = blockIdx.x;                       // 0..8191
    const float* src = (row < NROWS) ? dec + (size_t)row * D_MODEL
                                     : enc + (size_t)(row - NROWS) * D_MODEL;
    unsigned short* dst = (row < NROWS) ? q_ln + (size_t)row * D_MODEL
                                        : kv_ln + (size_t)(row - NROWS) * D_MODEL;
    int t = threadIdx.x;
    float4 x = ((const float4*)src)[t];
    float s  = x.x + x.y + x.z + x.w;
    float ss = x.x * x.x + x.y * x.y + x.z * x.z + x.w * x.w;
    #pragma unroll
    for (int off = 32; off > 0; off >>= 1) {
        s  += __shfl_down(s, off);
        ss += __shfl_down(ss, off);
    }
    __shared__ float red_s[4], red_ss[4];
    int wid = t >> 6, lane = t & 63;
    if (lane == 0) { red_s[wid] = s; red_ss[wid] = ss; }
    __syncthreads();
    if (t == 0) {
        float S = red_s[0] + red_s[1] + red_s[2] + red_s[3];
        float SS = red_ss[0] + red_ss[1] + red_ss[2] + red_ss[3];
        red_s[0] = S; red_ss[0] = SS;
    }
    __syncthreads();
    float mu  = red_s[0] * (1.0f / 1024.0f);
    float var = red_ss[0] * (1.0f / 1024.0f) - mu * mu;
    float rstd = rsqrtf(var + LN_EPS);
    float4 g = ((const float4*)gamma)[t];
    float4 bb = ((const float4*)beta)[t];
    ushort4 u;
    u.x = f2bf((x.x - mu) * rstd * g.x + bb.x);
    u.y = f2bf((x.y - mu) * rstd * g.y + bb.y);
    u.z = f2bf((x.z - mu) * rstd * g.z + bb.z);
    u.w = f2bf((x.w - mu) * rstd * g.w + bb.w);
    ((ushort4*)dst)[t] = u;
}

// ===========================================================================
// Shared MFMA GEMM pattern: C(128x128) = A(128xK) @ W^T(128xK), bf16 in.
// 256 thr = 4 waves (2x2); wave does 64x64 as 4x4 MFMA 16x16 tiles.
//
// R4-R6 finding: array accumulators (f32x4 acc[4][4]) in the macro'd loop
// were lowered to SCRATCH (VGPR_Count=68, 1.23 GB HBM WRITE of spill
// traffic, MfmaUtil 2.8%, kernel HBM-bound at 4.5 TB/s). Fix: 16 NAMED
// f32x4 accumulators + fully expanded MFMA statements — scalars are SSA
// values, guaranteed register allocation. No arrays anywhere in hot path.
// ===========================================================================
#define GSTR 72
#define CSTR 136   // multiple of 8 (16B-aligned rows for u16x8 epilogue reads)

union alignas(16) GemmSmem {
    struct { unsigned short A[128 * GSTR]; unsigned short B[128 * GSTR]; } ab;
    unsigned short C[128 * CSTR];   // 34816 shorts <= 36864
};

#define MF(a, b, d) __builtin_amdgcn_mfma_f32_16x16x32_bf16((a), (b), (d), 0, 0, 0)

#define GEMM_KH(kh)                                                            \
    {                                                                          \
        const unsigned short* Arow_ = &As[(wr * 64 + c) * GSTR + (kh) * 32 + quad * 8]; \
        const unsigned short* Brow_ = &Bs[(wc * 64 + c) * GSTR + (kh) * 32 + quad * 8]; \
        bf16x8 f0 = *(const bf16x8*)(Arow_);                                   \
        bf16x8 f1 = *(const bf16x8*)(Arow_ + 16 * GSTR);                       \
        bf16x8 f2 = *(const bf16x8*)(Arow_ + 32 * GSTR);                       \
        bf16x8 f3 = *(const bf16x8*)(Arow_ + 48 * GSTR);                       \
        bf16x8 g0 = *(const bf16x8*)(Brow_);                                   \
        bf16x8 g1 = *(const bf16x8*)(Brow_ + 16 * GSTR);                       \
        bf16x8 g2 = *(const bf16x8*)(Brow_ + 32 * GSTR);                       \
        bf16x8 g3 = *(const bf16x8*)(Brow_ + 48 * GSTR);                       \
        a00 = MF(f0, g0, a00); a01 = MF(f0, g1, a01); a02 = MF(f0, g2, a02); a03 = MF(f0, g3, a03); \
        a10 = MF(f1, g0, a10); a11 = MF(f1, g1, a11); a12 = MF(f1, g2, a12); a13 = MF(f1, g3, a13); \
        a20 = MF(f2, g0, a20); a21 = MF(f2, g1, a21); a22 = MF(f2, g2, a22); a23 = MF(f2, g3, a23); \
        a30 = MF(f3, g0, a30); a31 = MF(f3, g1, a31); a32 = MF(f3, g2, a32); a33 = MF(f3, g3, a33); \
    }

#define GEMM_MAIN_LOOP(Aptr, Bptr)                                             \
    __shared__ GemmSmem smem;                                                  \
    unsigned short* As = smem.ab.A;                                            \
    unsigned short* Bs = smem.ab.B;                                            \
    int tid = threadIdx.x;                                                     \
    int wave = tid >> 6, lane = tid & 63, quad = lane >> 4, c = lane & 15;     \
    int wr = wave >> 1, wc = wave & 1;                                         \
    int colg = tid & 7, r0 = tid >> 3;                                         \
    const unsigned short* Ab = (Aptr) + (size_t)(rt * 128 + r0) * 1024 + colg * 8; \
    const unsigned short* Bb = (Bptr) + (size_t)(ct * 128 + r0) * 1024 + colg * 8; \
    f32x4 a00 = (f32x4)0.f, a01 = (f32x4)0.f, a02 = (f32x4)0.f, a03 = (f32x4)0.f; \
    f32x4 a10 = (f32x4)0.f, a11 = (f32x4)0.f, a12 = (f32x4)0.f, a13 = (f32x4)0.f; \
    f32x4 a20 = (f32x4)0.f, a21 = (f32x4)0.f, a22 = (f32x4)0.f, a23 = (f32x4)0.f; \
    f32x4 a30 = (f32x4)0.f, a31 = (f32x4)0.f, a32 = (f32x4)0.f, a33 = (f32x4)0.f; \
    for (int kt = 0; kt < 16; ++kt) {                                          \
        int k0 = kt * 64;                                                      \
        __syncthreads();                                                       \
        *(u16x8*)&As[(r0 +  0) * GSTR + colg * 8] = *(const u16x8*)(Ab + k0);  \
        *(u16x8*)&As[(r0 + 32) * GSTR + colg * 8] = *(const u16x8*)(Ab + 32768 + k0);  \
        *(u16x8*)&As[(r0 + 64) * GSTR + colg * 8] = *(const u16x8*)(Ab + 65536 + k0);  \
        *(u16x8*)&As[(r0 + 96) * GSTR + colg * 8] = *(const u16x8*)(Ab + 98304 + k0);  \
        *(u16x8*)&Bs[(r0 +  0) * GSTR + colg * 8] = *(const u16x8*)(Bb + k0);  \
        *(u16x8*)&Bs[(r0 + 32) * GSTR + colg * 8] = *(const u16x8*)(Bb + 32768 + k0);  \
        *(u16x8*)&Bs[(r0 + 64) * GSTR + colg * 8] = *(const u16x8*)(Bb + 65536 + k0);  \
        *(u16x8*)&Bs[(r0 + 96) * GSTR + colg * 8] = *(const u16x8*)(Bb + 98304 + k0);  \
        __syncthreads();                                                       \
        GEMM_KH(0)                                                             \
        GEMM_KH(1)                                                             \
    }

// ---------------------------------------------------------------------------
// QKV GEMM (MFMA) + fused RoPE, LDS-bounce epilogue with wide stores.
// 1-D grid of 768, swizzled into 8(ct)x4(rt) super-tiles for L2 locality.
// ---------------------------------------------------------------------------
#define ROPE_REG(i, reg, A0, A1, A2, A3)                                       \
    {                                                                          \
        int mloc = wr * 64 + (i) * 16 + quad * 4 + (reg);                      \
        int crow = mloc * CSTR + wc * 64;                                      \
        float fl = (float)((rt * 128 + mloc) & 511);                           \
        float aa0 = fl * inv0, aa1 = fl * inv1;                                \
        float c0 = cosf(aa0), s0 = sinf(aa0);                                  \
        float c1 = cosf(aa1), s1 = sinf(aa1);                                  \
        float e0 = A0[(reg)], o0 = A2[(reg)];                                  \
        float e1 = A1[(reg)], o1 = A3[(reg)];                                  \
        smem.C[crow + c]      = f2bf(e0 * c0 - o0 * s0);                       \
        smem.C[crow + 32 + c] = f2bf(e0 * s0 + o0 * c0);                       \
        smem.C[crow + 16 + c] = f2bf(e1 * c1 - o1 * s1);                       \
        smem.C[crow + 48 + c] = f2bf(e1 * s1 + o1 * c1);                       \
    }
#define ROPE_ROW(i, A0, A1, A2, A3)                                            \
    ROPE_REG(i, 0, A0, A1, A2, A3) ROPE_REG(i, 1, A0, A1, A2, A3)              \
    ROPE_REG(i, 2, A0, A1, A2, A3) ROPE_REG(i, 3, A0, A1, A2, A3)

#define VSEC_REG(i, reg, A0, A1, A2, A3)                                       \
    {                                                                          \
        int crow = (wr * 64 + (i) * 16 + quad * 4 + (reg)) * CSTR + wc * 64;   \
        smem.C[crow + c]      = f2bf(A0[(reg)]);                               \
        smem.C[crow + 16 + c] = f2bf(A1[(reg)]);                               \
        smem.C[crow + 32 + c] = f2bf(A2[(reg)]);                               \
        smem.C[crow + 48 + c] = f2bf(A3[(reg)]);                               \
    }
#define VSEC_ROW(i, A0, A1, A2, A3)                                            \
    VSEC_REG(i, 0, A0, A1, A2, A3) VSEC_REG(i, 1, A0, A1, A2, A3)              \
    VSEC_REG(i, 2, A0, A1, A2, A3) VSEC_REG(i, 3, A0, A1, A2, A3)

__global__ __launch_bounds__(256, 1)
void qkv_gemm_mfma(const unsigned short* __restrict__ q_ln,
                   const unsigned short* __restrict__ kv_ln,
                   const unsigned short* __restrict__ Wb,
                   unsigned short* __restrict__ qo,
                   unsigned short* __restrict__ ko,
                   unsigned short* __restrict__ vo) {
    int bid = blockIdx.x;               // 0..767
    int st = bid >> 5, in = bid & 31;   // 24 super-tiles of 32 blocks
    int stc = st % 3, str = st / 3;
    int ct = stc * 8 + (in & 7);        // 0..23
    int rt = str * 4 + (in >> 3);       // 0..31
    int n0 = ct * 128;
    int section = n0 >> 10;             // 0=q 1=k 2=v (uniform per block)
    const unsigned short* A = (section == 0) ? q_ln : kv_ln;

    GEMM_MAIN_LOOP(A, Wb)

    // ---- epilogue: RoPE in-register, bounce through LDS, wide stores ----
    __syncthreads();                    // all waves done reading As/Bs
    if (section == 2) {
        VSEC_ROW(0, a00, a01, a02, a03)
        VSEC_ROW(1, a10, a11, a12, a13)
        VSEC_ROW(2, a20, a21, a22, a23)
        VSEC_ROW(3, a30, a31, a32, a33)
    } else {
        float inv0 = expf(-0.2878231366f * (float)c);          // 10000^(-c/32)
        float inv1 = expf(-0.2878231366f * (float)(16 + c));
        ROPE_ROW(0, a00, a01, a02, a03)
        ROPE_ROW(1, a10, a11, a12, a13)
        ROPE_ROW(2, a20, a21, a22, a23)
        ROPE_ROW(3, a30, a31, a32, a33)
    }
    __syncthreads();

    unsigned short* outp = (section == 0) ? qo : (section == 1) ? ko : vo;
    int rr = tid >> 1, ch = tid & 1;    // row 0..127, head-half 0/1
    int mm = rt * 128 + rr;
    int bb = mm >> 9, ll = mm & 511;
    int h = ((n0 & 1023) >> 6) + ch;
    unsigned short* orow = outp + (((size_t)bb * NHEADS + h) * SEQ + ll) * HDIM;
    const unsigned short* csrc = &smem.C[rr * CSTR + ch * 64];
    #pragma unroll
    for (int kc = 0; kc < 8; ++kc)
        *(u16x8*)(orow + kc * 8) = *(const u16x8*)(csrc + kc * 8);
}

// ---------------------------------------------------------------------------
// Projection 1 (MFMA): t = att @ Wout^T + b_out -> fp32 t_proj + bf16 t_bf
// grid (8, 32)
// ---------------------------------------------------------------------------
#define OUT1_REG(mb, reg, n, Aij)                                              \
    {                                                                          \
        float v = Aij[(reg)] + bo;                                             \
        t_proj[(size_t)((mb) + (reg)) * 1024 + (n)] = v;                       \
        t_bf[(size_t)((mb) + (reg)) * 1024 + (n)] = f2bf(v);                   \
    }
#define OUT1_TILE(i, j, Aij)                                                   \
    {                                                                          \
        int n = ct * 128 + wc * 64 + (j) * 16 + c;                             \
        float bo = b_out[n];                                                   \
        int mb = rt * 128 + wr * 64 + (i) * 16 + quad * 4;                     \
        OUT1_REG(mb, 0, n, Aij) OUT1_REG(mb, 1, n, Aij)                        \
        OUT1_REG(mb, 2, n, Aij) OUT1_REG(mb, 3, n, Aij)                        \
    }

__global__ __launch_bounds__(256, 1)
void out_gemm1_mfma(const unsigned short* __restrict__ att,
                    const unsigned short* __restrict__ Wob,
                    const float* __restrict__ b_out,
                    float* __restrict__ t_proj,
                    unsigned short* __restrict__ t_bf) {
    int ct = blockIdx.x, rt = blockIdx.y;

    GEMM_MAIN_LOOP(att, Wob)

    OUT1_TILE(0, 0, a00) OUT1_TILE(0, 1, a01) OUT1_TILE(0, 2, a02) OUT1_TILE(0, 3, a03)
    OUT1_TILE(1, 0, a10) OUT1_TILE(1, 1, a11) OUT1_TILE(1, 2, a12) OUT1_TILE(1, 3, a13)
    OUT1_TILE(2, 0, a20) OUT1_TILE(2, 1, a21) OUT1_TILE(2, 2, a22) OUT1_TILE(2, 3, a23)
    OUT1_TILE(3, 0, a30) OUT1_TILE(3, 1, a31) OUT1_TILE(3, 2, a32) OUT1_TILE(3, 3, a33)
}

// ---------------------------------------------------------------------------
// Projection 2 (MFMA): gz = t_bf @ Wgate^T + b_gate;
// out = sigmoid(gz)*t + (1-sigmoid)*residual
// grid (8, 32)
// ---------------------------------------------------------------------------
#define OUT2_REG(mb, reg, n, Aij)                                              \
    {                                                                          \
        float gz = Aij[(reg)] + bg;                                            \
        float g = 1.0f / (1.0f + expf(-gz));                                   \
        size_t idx = (size_t)((mb) + (reg)) * 1024 + (n);                      \
        float tv = t_proj[idx];                                                \
        float rv = residual[idx];                                              \
        out[idx] = g * tv + (1.0f - g) * rv;                                   \
    }
#define OUT2_TILE(i, j, Aij)                                                   \
    {                                                                          \
        int n = ct * 128 + wc * 64 + (j) * 16 + c;                             \
        float bg = b_gate[n];                                                  \
        int mb = rt * 128 + wr * 64 + (i) * 16 + quad * 4;                     \
        OUT2_REG(mb, 0, n, Aij) OUT2_REG(mb, 1, n, Aij)                        \
        OUT2_REG(mb, 2, n, Aij) OUT2_REG(mb, 3, n, Aij)                        \
    }

__global__ __launch_bounds__(256, 1)
void out_gemm2_mfma(const unsigned short* __restrict__ t_bf,
                    const unsigned short* __restrict__ Wgb,
                    const float* __restrict__ b_gate,
                    const float* __restrict__ t_proj,
                    const float* __restrict__ residual,
                    float* __restrict__ out) {
    int ct = blockIdx.x, rt = blockIdx.y;

    GEMM_MAIN_LOOP(t_bf, Wgb)

    OUT2_TILE(0, 0, a00) OUT2_TILE(0, 1, a01) OUT2_TILE(0, 2, a02) OUT2_TILE(0, 3, a03)
    OUT2_TILE(1, 0, a10) OUT2_TILE(1, 1, a11) OUT2_TILE(1, 2, a12) OUT2_TILE(1, 3, a13)
    OUT2_TILE(2, 0, a20) OUT2_TILE(2, 1, a21) OUT2_TILE(2, 2, a22) OUT2_TILE(2, 3, a23)
    OUT2_TILE(3, 0, a30) OUT2_TILE(3, 1, a31) OUT2_TILE(3, 2, a32) OUT2_TILE(3, 3, a33)
}

// ---------------------------------------------------------------------------
// Flash attention, bf16 MFMA (16x16x32) — unchanged (verified)
// ---------------------------------------------------------------------------
#define KSTR 72

__global__ __launch_bounds__(256)
void attn_kernel(const unsigned short* __restrict__ q,
                 const unsigned short* __restrict__ k,
                 const unsigned short* __restrict__ v,
                 const float* __restrict__ bias,
                 unsigned short* __restrict__ attended) {
    int qt = blockIdx.x, h = blockIdx.y, b = blockIdx.z;
    __shared__ unsigned short Ks[64 * KSTR];
    __shared__ unsigned short Vt[64 * KSTR];
    __shared__ unsigned short Ps[64 * KSTR];
    __shared__ float af[64];
    __shared__ float lf[64];

    int tid = threadIdx.x;
    int wave = tid >> 6, lane = tid & 63;
    int quad = lane >> 4, c = lane & 15;
    int wb = wave * 16;
    size_t headbase = (((size_t)b * NHEADS + h) * SEQ) * HDIM;
    int q0 = qt * 64;

    const unsigned short* qrow = q + headbase + (size_t)(q0 + wb + c) * HDIM;
    bf16x8 aq0 = *(const bf16x8*)(qrow + quad * 8);
    bf16x8 aq1 = *(const bf16x8*)(qrow + 32 + quad * 8);

    int sr = tid >> 2, sc0 = (tid & 3) * 16;

    f32x4 oacc[4];
    #pragma unroll
    for (int t = 0; t < 4; ++t) oacc[t] = (f32x4)0.f;
    float mrow[4], lrow[4];
    #pragma unroll
    for (int r = 0; r < 4; ++r) { mrow[r] = -1e30f; lrow[r] = 0.f; }

    for (int kt = 0; kt < 8; ++kt) {
        int kv0 = kt * 64;
        __syncthreads();
        {
            const unsigned short* krow = k + headbase + (size_t)(kv0 + sr) * HDIM + sc0;
            const unsigned short* vrow = v + headbase + (size_t)(kv0 + sr) * HDIM + sc0;
            u16x8 ka = *(const u16x8*)(krow);
            u16x8 kb2 = *(const u16x8*)(krow + 8);
            u16x8 va = *(const u16x8*)(vrow);
            u16x8 vb2 = *(const u16x8*)(vrow + 8);
            *(u16x8*)&Ks[sr * KSTR + sc0] = ka;
            *(u16x8*)&Ks[sr * KSTR + sc0 + 8] = kb2;
            #pragma unroll
            for (int j = 0; j < 8; ++j) Vt[(sc0 + j) * KSTR + sr] = va[j];
            #pragma unroll
            for (int j = 0; j < 8; ++j) Vt[(sc0 + 8 + j) * KSTR + sr] = vb2[j];
        }
        __syncthreads();

        f32x4 sacc[4];
        #pragma unroll
        for (int nt = 0; nt < 4; ++nt) {
            const unsigned short* kbase = &Ks[(nt * 16 + c) * KSTR];
            bf16x8 b0 = *(const bf16x8*)(kbase + quad * 8);
            bf16x8 b1 = *(const bf16x8*)(kbase + 32 + quad * 8);
            f32x4 a = (f32x4)0.f;
            a = __builtin_amdgcn_mfma_f32_16x16x32_bf16(aq0, b0, a, 0, 0, 0);
            a = __builtin_amdgcn_mfma_f32_16x16x32_bf16(aq1, b1, a, 0, 0, 0);
            sacc[nt] = a;
        }

        const float* bbase = bias + (size_t)(q0 + wb + quad * 4) * 512 + kv0 + c;
        float tmax[4];
        #pragma unroll
        for (int r = 0; r < 4; ++r) tmax[r] = -1e30f;
        #pragma unroll
        for (int nt = 0; nt < 4; ++nt)
            #pragma unroll
            for (int r = 0; r < 4; ++r) {
                float s = sacc[nt][r] * SCALE + bbase[(size_t)r * 512 + nt * 16];
                sacc[nt][r] = s;
                tmax[r] = fmaxf(tmax[r], s);
            }
        #pragma unroll
        for (int r = 0; r < 4; ++r) {
            float t = tmax[r];
            t = fmaxf(t, __shfl_xor(t, 1));
            t = fmaxf(t, __shfl_xor(t, 2));
            t = fmaxf(t, __shfl_xor(t, 4));
            t = fmaxf(t, __shfl_xor(t, 8));
            tmax[r] = t;
        }
        float alpha[4];
        #pragma unroll
        for (int r = 0; r < 4; ++r) {
            float mnew = fmaxf(mrow[r], tmax[r]);
            alpha[r] = __expf(mrow[r] - mnew);
            mrow[r] = mnew;
        }
        float tsum[4];
        #pragma unroll
        for (int r = 0; r < 4; ++r) tsum[r] = 0.f;
        #pragma unroll
        for (int nt = 0; nt < 4; ++nt)
            #pragma unroll
            for (int r = 0; r < 4; ++r) {
                float p = __expf(sacc[nt][r] - mrow[r]);
                tsum[r] += p;
                Ps[(wb + quad * 4 + r) * KSTR + nt * 16 + c] = f2bf(p);
            }
        #pragma unroll
        for (int r = 0; r < 4; ++r) {
            float t = tsum[r];
            t += __shfl_xor(t, 1);
            t += __shfl_xor(t, 2);
            t += __shfl_xor(t, 4);
            t += __shfl_xor(t, 8);
            lrow[r] = lrow[r] * alpha[r] + t;
        }
        if (c == 0) {
            f32x4 av;
            av[0] = alpha[0]; av[1] = alpha[1]; av[2] = alpha[2]; av[3] = alpha[3];
            *(f32x4*)&af[wb + quad * 4] = av;
        }
        float myalpha = af[wb + c];
        #pragma unroll
        for (int t = 0; t < 4; ++t) oacc[t] *= myalpha;

        bf16x8 pb0 = *(const bf16x8*)&Ps[(wb + c) * KSTR + quad * 8];
        bf16x8 pb1 = *(const bf16x8*)&Ps[(wb + c) * KSTR + 32 + quad * 8];
        #pragma unroll
        for (int t = 0; t < 4; ++t) {
            const unsigned short* vbase = &Vt[(t * 16 + c) * KSTR];
            bf16x8 a0 = *(const bf16x8*)(vbase + quad * 8);
            bf16x8 a1 = *(const bf16x8*)(vbase + 32 + quad * 8);
            oacc[t] = __builtin_amdgcn_mfma_f32_16x16x32_bf16(a0, pb0, oacc[t], 0, 0, 0);
            oacc[t] = __builtin_amdgcn_mfma_f32_16x16x32_bf16(a1, pb1, oacc[t], 0, 0, 0);
        }
    }

    if (c == 0) {
        f32x4 lv;
        lv[0] = lrow[0]; lv[1] = lrow[1]; lv[2] = lrow[2]; lv[3] = lrow[3];
        *(f32x4*)&lf[wb + quad * 4] = lv;
    }
    float invl = 1.0f / lf[wb + c];
    unsigned short* drow = attended + ((size_t)b * SEQ + (q0 + wb + c)) * D_MODEL + h * HDIM;
    #pragma unroll
    for (int t = 0; t < 4; ++t) {
        ushort4 o;
        o.x = f2bf(oacc[t][0] * invl);
        o.y = f2bf(oacc[t][1] * invl);
        o.z = f2bf(oacc[t][2] * invl);
        o.w = f2bf(oacc[t][3] * invl);
        *(ushort4*)(drow + t * 16 + quad * 4) = o;
    }
}

extern "C" void kernel_launch(void* const* d_in, const int* in_sizes, int n_in,
                              void* d_out, int out_size, void* d_ws, size_t ws_size,
                              hipStream_t stream) {
    const float* dec    = (const float*)d_in[0];
    const float* enc    = (const float*)d_in[1];
    const float* Wqkv   = (const float*)d_in[2];
    const float* Wout   = (const float*)d_in[3];
    const float* b_out  = (const float*)d_in[4];
    const float* Wgate  = (const float*)d_in[5];
    const float* b_gate = (const float*)d_in[6];
    const float* gamma  = (const float*)d_in[7];
    const float* beta   = (const float*)d_in[8];
    float* out = (float*)d_out;

    char* ws = (char*)d_ws;
    const size_t MB = 1024 * 1024;
    unsigned short* q_ln    = (unsigned short*)(ws + 0 * MB);
    unsigned short* kv_ln   = (unsigned short*)(ws + 8 * MB);
    unsigned short* qb      = (unsigned short*)(ws + 16 * MB);
    unsigned short* kb      = (unsigned short*)(ws + 24 * MB);
    unsigned short* vb      = (unsigned short*)(ws + 32 * MB);
    unsigned short* Wqkv_bf = (unsigned short*)(ws + 40 * MB);
    float*          bias    = (float*)(ws + 46 * MB);
    unsigned short* att     = (unsigned short*)(ws + 0 * MB);
    float*          t_proj  = (float*)(ws + 8 * MB);
    unsigned short* t_bf    = (unsigned short*)(ws + 24 * MB);
    unsigned short* Wout_bf = (unsigned short*)(ws + 32 * MB);
    unsigned short* Wgate_bf= (unsigned short*)(ws + 34 * MB);

    bias_kernel<<<1024, 256, 0, stream>>>(bias);
    ln_kernel<<<8192, 256, 0, stream>>>(dec, enc, gamma, beta, q_ln, kv_ln);
    f32_to_bf16<<<3072, 256, 0, stream>>>(Wqkv, Wqkv_bf, 3072 * 1024 / 4);
    qkv_gemm_mfma<<<768, 256, 0, stream>>>(q_ln, kv_ln, Wqkv_bf, qb, kb, vb);
    attn_kernel<<<dim3(8, 16, 8), 256, 0, stream>>>(qb, kb, vb, bias, att);
    f32_to_bf16<<<1024, 256, 0, stream>>>(Wout, Wout_bf, 1024 * 1024 / 4);
    f32_to_bf16<<<1024, 256, 0, stream>>>(Wgate, Wgate_bf, 1024 * 1024 / 4);
    out_gemm1_mfma<<<dim3(8, 32), 256, 0, stream>>>(att, Wout_bf, b_out, t_proj, t_bf);
    out_gemm2_mfma<<<dim3(8, 32), 256, 0, stream>>>(t_bf, Wgate_bf, b_gate, t_proj, dec, out);
}